// Round 1
// baseline (486.587 us; speedup 1.0000x reference)
//
#include <hip/hip_runtime.h>

#define Bn 8
#define Ln 2048
#define Pn 576
#define Vn 32000
#define Dn 2560
#define Tn (Ln - 1 + Pn)          // 2623
#define IGNORE_INDEX (-100)

// One block per output row (b, t). 640 threads x float4 = 2560 floats = one row.
// The img-vs-token branch is uniform across the whole block (depends only on b,t),
// so no divergence. Embed-table gather rows are contiguous 10 KB reads -> coalesced.
__global__ __launch_bounds__(640) void splice_kernel(
    const float* __restrict__ embed_table,     // (V, D)
    const float* __restrict__ image_features,  // (B, P, D)
    const int*   __restrict__ input_ids,       // (B, L)
    const int*   __restrict__ labels,          // (B, L)
    const int*   __restrict__ img_pos,         // (B,)
    float* __restrict__ out)                   // embeds | labels | mask | pos_ids
{
    const int t = blockIdx.x;      // [0, T)
    const int b = blockIdx.y;      // [0, B)
    const int pos = img_pos[b];

    const bool is_img = (t >= pos) && (t < pos + Pn);

    const float4* __restrict__ src;
    int tok_idx = 0;
    if (is_img) {
        const int img_idx = t - pos;  // already in [0, P)
        src = (const float4*)(image_features + ((size_t)b * Pn + img_idx) * Dn);
    } else {
        tok_idx = (t < pos) ? t : (t - Pn + 1);
        tok_idx = min(max(tok_idx, 0), Ln - 1);
        const int id = input_ids[b * Ln + tok_idx];
        src = (const float4*)(embed_table + (size_t)id * Dn);
    }

    float4* __restrict__ dst = (float4*)(out + ((size_t)b * Tn + t) * Dn);
    dst[threadIdx.x] = src[threadIdx.x];   // 640 threads x 16B = full row

    if (threadIdx.x == 0) {
        const size_t nBT  = (size_t)Bn * Tn;
        const size_t base = nBT * Dn;
        const size_t idx  = (size_t)b * Tn + t;
        float lab;
        if (is_img) {
            lab = (float)IGNORE_INDEX;
        } else {
            lab = (float)labels[b * Ln + tok_idx];
        }
        out[base + idx]            = lab;        // new_labels (as f32)
        out[base + nBT + idx]      = 1.0f;       // attention_mask
        out[base + 2 * nBT + idx]  = (float)t;   // position_ids
    }
}

extern "C" void kernel_launch(void* const* d_in, const int* in_sizes, int n_in,
                              void* d_out, int out_size, void* d_ws, size_t ws_size,
                              hipStream_t stream) {
    const float* embed_table    = (const float*)d_in[0];
    const float* image_features = (const float*)d_in[1];
    const int*   input_ids      = (const int*)d_in[2];
    const int*   labels         = (const int*)d_in[3];
    const int*   img_pos        = (const int*)d_in[4];
    float* out = (float*)d_out;

    dim3 grid(Tn, Bn);
    dim3 block(640);
    splice_kernel<<<grid, block, 0, stream>>>(embed_table, image_features,
                                              input_ids, labels, img_pos, out);
}